// Round 2
// baseline (298.806 us; speedup 1.0000x reference)
//
#include <hip/hip_runtime.h>
#include <hip/hip_bf16.h>

#define N_NODES 50000
#define N_EDGES 800000
#define D 128

typedef __attribute__((ext_vector_type(8))) short bf16x8;
typedef __attribute__((ext_vector_type(4))) float f32x4;

__device__ inline unsigned short f2bf(float f) {
  unsigned u = __float_as_uint(f);
  unsigned r = (u + 0x7FFFu + ((u >> 16) & 1u)) >> 16;
  return (unsigned short)r;
}

// ---------------- CSR build ----------------

__global__ void hist_kernel(const int* __restrict__ dst, int* __restrict__ count) {
  int e = blockIdx.x * blockDim.x + threadIdx.x;
  if (e < N_EDGES) atomicAdd(&count[dst[e]], 1);
}

// One block, 1024 threads; thread t owns count[t*49 .. t*49+48].
// Two barriers total (vs 49 iterations x 6 barriers before).
__global__ __launch_bounds__(1024) void scan_kernel(const int* __restrict__ count,
                                                    int* __restrict__ row_start,
                                                    int* __restrict__ cursor) {
  __shared__ int wsums[16];
  const int CH = 49;  // 1024*49 = 50176 >= 50000
  int t = threadIdx.x;
  int lane = t & 63, wid = t >> 6;
  int base = t * CH;
  int s = 0;
#pragma unroll 8
  for (int i = 0; i < CH; ++i) {
    int idx = base + i;
    if (idx < N_NODES) s += count[idx];
  }
  int incl = s;
#pragma unroll
  for (int off = 1; off < 64; off <<= 1) {
    int y = __shfl_up(incl, off, 64);
    if (lane >= off) incl += y;
  }
  if (lane == 63) wsums[wid] = incl;
  __syncthreads();
  if (t < 16) {
    int v = wsums[t];
    int sc = v;
#pragma unroll
    for (int off = 1; off < 16; off <<= 1) {
      int y = __shfl_up(sc, off, 64);
      if (t >= off) sc += y;
    }
    wsums[t] = sc - v;  // exclusive prefix of wave sums
  }
  __syncthreads();
  int run = incl - s + wsums[wid];  // exclusive prefix for this thread
#pragma unroll 8
  for (int i = 0; i < CH; ++i) {
    int idx = base + i;
    if (idx < N_NODES) {
      row_start[idx] = run;
      cursor[idx] = run;
      run += count[idx];
    }
  }
  if (t == 1023) row_start[N_NODES] = run;
}

__global__ void scatter_kernel(const int* __restrict__ src, const int* __restrict__ dst,
                               const float* __restrict__ w, int* __restrict__ cursor,
                               int* __restrict__ csr_src, float* __restrict__ csr_w) {
  int e = blockIdx.x * blockDim.x + threadIdx.x;
  if (e < N_EDGES) {
    int pos = atomicAdd(&cursor[dst[e]], 1);
    csr_src[pos] = src[e];
    csr_w[pos]   = w[e];
  }
}

// ---------------- dtype conversions ----------------

__global__ void convw_kernel(const float* __restrict__ Wm, unsigned short* __restrict__ W_bf) {
  int i = blockIdx.x * blockDim.x + threadIdx.x;
  if (i < D * D) W_bf[i] = f2bf(Wm[i]);
}

// h (f32 [N][128]) -> packed bf16 pairs (uint [N][64]); float4 -> uint2 per thread
__global__ void convh_kernel(const float* __restrict__ h, unsigned* __restrict__ h_bf) {
  int i = blockIdx.x * blockDim.x + threadIdx.x;
  if (i < N_NODES * D / 4) {
    float4 f = ((const float4*)h)[i];
    unsigned lo = ((unsigned)f2bf(f.y) << 16) | f2bf(f.x);
    unsigned hi = ((unsigned)f2bf(f.w) << 16) | f2bf(f.z);
    ((uint2*)h_bf)[i] = make_uint2(lo, hi);
  }
}

// ---------------- aggregate: mean of h[src]*w by dst, then tanh ----------------
// bf16 path: one 64-lane wave per node; lane owns channels {2*lane, 2*lane+1}
// packed in one uint. Gather traffic halves vs f32.
__global__ __launch_bounds__(256) void aggregate_bf_kernel(const unsigned* __restrict__ h_bf,
                                                           const int* __restrict__ csr_src,
                                                           const float* __restrict__ csr_w,
                                                           const int* __restrict__ row_start,
                                                           float* __restrict__ hact) {
  int node = blockIdx.x * 4 + (threadIdx.x >> 6);
  int lane = threadIdx.x & 63;
  if (node >= N_NODES) return;
  int beg = row_start[node], end = row_start[node + 1];
  float a0 = 0.f, a1 = 0.f;
  int e = beg;
  for (; e + 4 <= end; e += 4) {
    int   s0 = csr_src[e],   s1 = csr_src[e+1], s2 = csr_src[e+2], s3 = csr_src[e+3];
    float w0 = csr_w[e],     w1 = csr_w[e+1],   w2 = csr_w[e+2],   w3 = csr_w[e+3];
    unsigned v0 = h_bf[s0 * 64 + lane];
    unsigned v1 = h_bf[s1 * 64 + lane];
    unsigned v2 = h_bf[s2 * 64 + lane];
    unsigned v3 = h_bf[s3 * 64 + lane];
    a0 = fmaf(__uint_as_float(v0 << 16), w0, a0);
    a1 = fmaf(__uint_as_float(v0 & 0xFFFF0000u), w0, a1);
    a0 = fmaf(__uint_as_float(v1 << 16), w1, a0);
    a1 = fmaf(__uint_as_float(v1 & 0xFFFF0000u), w1, a1);
    a0 = fmaf(__uint_as_float(v2 << 16), w2, a0);
    a1 = fmaf(__uint_as_float(v2 & 0xFFFF0000u), w2, a1);
    a0 = fmaf(__uint_as_float(v3 << 16), w3, a0);
    a1 = fmaf(__uint_as_float(v3 & 0xFFFF0000u), w3, a1);
  }
  for (; e < end; ++e) {
    float we = csr_w[e];
    unsigned v = h_bf[csr_src[e] * 64 + lane];
    a0 = fmaf(__uint_as_float(v << 16), we, a0);
    a1 = fmaf(__uint_as_float(v & 0xFFFF0000u), we, a1);
  }
  int deg = end - beg;
  float inv = (deg > 0) ? 1.f / (float)deg : 0.f;
  float2 r;
  r.x = tanhf(a0 * inv);
  r.y = tanhf(a1 * inv);
  ((float2*)hact)[node * 64 + lane] = r;
}

// f32 fallback (used only if ws too small for the bf16 h table)
__global__ __launch_bounds__(128) void aggregate_f32_kernel(const float* __restrict__ h,
                                                            const int* __restrict__ csr_src,
                                                            const float* __restrict__ csr_w,
                                                            const int* __restrict__ row_start,
                                                            float* __restrict__ hact) {
  int n = blockIdx.x;
  int lane = threadIdx.x;
  int beg = row_start[n], end = row_start[n + 1];
  float acc = 0.f;
  int e = beg;
  for (; e + 4 <= end; e += 4) {
    int   s0 = csr_src[e],   s1 = csr_src[e+1], s2 = csr_src[e+2], s3 = csr_src[e+3];
    float w0 = csr_w[e],     w1 = csr_w[e+1],   w2 = csr_w[e+2],   w3 = csr_w[e+3];
    acc = fmaf(h[s0 * D + lane], w0, acc);
    acc = fmaf(h[s1 * D + lane], w1, acc);
    acc = fmaf(h[s2 * D + lane], w2, acc);
    acc = fmaf(h[s3 * D + lane], w3, acc);
  }
  for (; e < end; ++e) acc = fmaf(h[csr_src[e] * D + lane], csr_w[e], acc);
  int deg = end - beg;
  float m = (deg > 0) ? acc / (float)deg : 0.f;
  hact[n * D + lane] = tanhf(m);
}

// ---------------- out = tanh-act @ W^T + b via MFMA bf16, in place on d_out ----
// 4 waves/block, wave = 16 nodes x 128 outputs. No LDS. A from d_out (f32,
// inline cvt), B from pre-converted bf16 W (16B frag loads). Safe in-place:
// each wave reads only its own 16 rows into registers before storing them.
__global__ __launch_bounds__(256) void gemm_kernel(const float* __restrict__ hact,
                                                   const unsigned short* __restrict__ W_bf,
                                                   const float* __restrict__ bias,
                                                   float* __restrict__ out) {
  int lane = threadIdx.x & 63;
  int wid  = threadIdx.x >> 6;
  int n_base = blockIdx.x * 64 + wid * 16;
  int m  = lane & 15;   // A row / D col index
  int kg = lane >> 4;   // k-group (8 elems each)
  int n = n_base + m;
  int n_c = (n < N_NODES) ? n : (N_NODES - 1);

  bf16x8 afrag[4];
  const float* arow = hact + (size_t)n_c * D;
#pragma unroll
  for (int kc = 0; kc < 4; ++kc) {
    int k0 = kc * 32 + kg * 8;
    float4 lo = *(const float4*)(arow + k0);
    float4 hi = *(const float4*)(arow + k0 + 4);
    bf16x8 a;
    a[0] = (short)f2bf(lo.x); a[1] = (short)f2bf(lo.y);
    a[2] = (short)f2bf(lo.z); a[3] = (short)f2bf(lo.w);
    a[4] = (short)f2bf(hi.x); a[5] = (short)f2bf(hi.y);
    a[6] = (short)f2bf(hi.z); a[7] = (short)f2bf(hi.w);
    afrag[kc] = a;
  }

#pragma unroll
  for (int jt = 0; jt < 8; ++jt) {
    int j = jt * 16 + m;
    const unsigned short* wrow = W_bf + j * D;
    f32x4 acc = {0.f, 0.f, 0.f, 0.f};
#pragma unroll
    for (int kc = 0; kc < 4; ++kc) {
      bf16x8 b = *(const bf16x8*)(wrow + kc * 32 + kg * 8);
      acc = __builtin_amdgcn_mfma_f32_16x16x32_bf16(afrag[kc], b, acc, 0, 0, 0);
    }
    float bj = bias[j];
#pragma unroll
    for (int r = 0; r < 4; ++r) {
      int nn = n_base + kg * 4 + r;  // C/D: col=lane&15, row=(lane>>4)*4+reg
      if (nn < N_NODES) out[(size_t)nn * D + j] = acc[r] + bj;
    }
  }
}

extern "C" void kernel_launch(void* const* d_in, const int* in_sizes, int n_in,
                              void* d_out, int out_size, void* d_ws, size_t ws_size,
                              hipStream_t stream) {
  const float* h    = (const float*)d_in[0];
  const float* w    = (const float*)d_in[1];
  const int*   src  = (const int*)d_in[2];
  const int*   dst  = (const int*)d_in[3];
  const float* Wm   = (const float*)d_in[4];
  const float* bias = (const float*)d_in[5];
  float* out = (float*)d_out;

  // ws layout (16B-aligned):
  //   count:     [0,          200000)
  //   row_start: [200000,     400004)
  //   cursor:    [400016,     600016)
  //   csr_src:   [600016,     3800016)
  //   csr_w:     [3800016,    7000016)
  //   W_bf:      [7000016,    7032784)
  //   h_bf:      [7032784,    19832784)
  char* ws = (char*)d_ws;
  int*            count     = (int*)(ws);
  int*            row_start = (int*)(ws + 200000);
  int*            cursor    = (int*)(ws + 400016);
  int*            csr_src   = (int*)(ws + 600016);
  float*          csr_w     = (float*)(ws + 3800016);
  unsigned short* W_bf      = (unsigned short*)(ws + 7000016);
  unsigned*       h_bf      = (unsigned*)(ws + 7032784);

  bool use_bf_h = (ws_size == 0) || (ws_size >= 19832784ull);

  hipMemsetAsync(count, 0, N_NODES * sizeof(int), stream);
  convw_kernel<<<(D * D + 255) / 256, 256, 0, stream>>>(Wm, W_bf);
  if (use_bf_h)
    convh_kernel<<<(N_NODES * D / 4 + 255) / 256, 256, 0, stream>>>(h, h_bf);
  hist_kernel<<<(N_EDGES + 255) / 256, 256, 0, stream>>>(dst, count);
  scan_kernel<<<1, 1024, 0, stream>>>(count, row_start, cursor);
  scatter_kernel<<<(N_EDGES + 255) / 256, 256, 0, stream>>>(src, dst, w, cursor, csr_src, csr_w);
  if (use_bf_h)
    aggregate_bf_kernel<<<(N_NODES + 3) / 4, 256, 0, stream>>>(h_bf, csr_src, csr_w, row_start, out);
  else
    aggregate_f32_kernel<<<N_NODES, 128, 0, stream>>>(h, csr_src, csr_w, row_start, out);
  gemm_kernel<<<(N_NODES + 63) / 64, 256, 0, stream>>>(out, W_bf, bias, out);
}

// Round 3
// 179.694 us; speedup vs baseline: 1.6629x; 1.6629x over previous
//
#include <hip/hip_runtime.h>
#include <hip/hip_bf16.h>

#define N_NODES 50000
#define N_EDGES 800000
#define D 128
#define SCAN_BLOCKS 49   // 49 * 1024 = 50176 >= N_NODES (padded)
#define N_PAD 50176

typedef __attribute__((ext_vector_type(8))) short bf16x8;
typedef __attribute__((ext_vector_type(4))) float f32x4;

__device__ inline unsigned short f2bf(float f) {
  unsigned u = __float_as_uint(f);
  unsigned r = (u + 0x7FFFu + ((u >> 16) & 1u)) >> 16;
  return (unsigned short)r;
}

// ---------------- CSR build ----------------

__global__ void hist_kernel(const int* __restrict__ dst, int* __restrict__ count) {
  int e = blockIdx.x * blockDim.x + threadIdx.x;
  if (e < N_EDGES) atomicAdd(&count[dst[e]], 1);
}

// 49 blocks x 256 threads; each block sums 1024 counts (int4 coalesced).
__global__ __launch_bounds__(256) void scan_part1(const int4* __restrict__ count4,
                                                  int* __restrict__ blocksum) {
  __shared__ int wsum[4];
  int b = blockIdx.x, t = threadIdx.x;
  int lane = t & 63, wid = t >> 6;
  int4 v = count4[b * 256 + t];
  int s = v.x + v.y + v.z + v.w;
#pragma unroll
  for (int off = 32; off >= 1; off >>= 1) s += __shfl_xor(s, off, 64);
  if (lane == 0) wsum[wid] = s;
  __syncthreads();
  if (t == 0) blocksum[b] = wsum[0] + wsum[1] + wsum[2] + wsum[3];
}

// One wave scans the 49 block sums -> exclusive offsets.
__global__ __launch_bounds__(64) void scan_part2(const int* __restrict__ blocksum,
                                                 int* __restrict__ blockoff) {
  int t = threadIdx.x;
  int v = (t < SCAN_BLOCKS) ? blocksum[t] : 0;
  int incl = v;
#pragma unroll
  for (int off = 1; off < 64; off <<= 1) {
    int y = __shfl_up(incl, off, 64);
    if (t >= off) incl += y;
  }
  if (t < SCAN_BLOCKS) blockoff[t] = incl - v;
}

// Per-block exclusive scan + block offset; writes row_start & cursor (int4).
// Padded region (idx >= N_NODES) holds total -> row_start[N_NODES] valid.
__global__ __launch_bounds__(256) void scan_part3(const int4* __restrict__ count4,
                                                  const int* __restrict__ blockoff,
                                                  int4* __restrict__ row4,
                                                  int4* __restrict__ cur4) {
  __shared__ int wsum[4];
  int b = blockIdx.x, t = threadIdx.x;
  int lane = t & 63, wid = t >> 6;
  int4 v = count4[b * 256 + t];
  int s = v.x + v.y + v.z + v.w;
  int incl = s;
#pragma unroll
  for (int off = 1; off < 64; off <<= 1) {
    int y = __shfl_up(incl, off, 64);
    if (lane >= off) incl += y;
  }
  if (lane == 63) wsum[wid] = incl;
  __syncthreads();
  int woff = 0;
#pragma unroll
  for (int i = 0; i < 4; ++i) woff += (i < wid) ? wsum[i] : 0;
  int excl = incl - s + woff + blockoff[b];
  int4 p;
  p.x = excl;
  p.y = p.x + v.x;
  p.z = p.y + v.y;
  p.w = p.z + v.z;
  row4[b * 256 + t] = p;
  cur4[b * 256 + t] = p;
}

__global__ void scatter_kernel(const int* __restrict__ src, const int* __restrict__ dst,
                               const float* __restrict__ w, int* __restrict__ cursor,
                               int* __restrict__ csr_src, float* __restrict__ csr_w) {
  int e = blockIdx.x * blockDim.x + threadIdx.x;
  if (e < N_EDGES) {
    int pos = atomicAdd(&cursor[dst[e]], 1);
    csr_src[pos] = src[e];
    csr_w[pos]   = w[e];
  }
}

// ---------------- dtype conversions ----------------

__global__ void convw_kernel(const float* __restrict__ Wm, unsigned short* __restrict__ W_bf) {
  int i = blockIdx.x * blockDim.x + threadIdx.x;
  if (i < D * D) W_bf[i] = f2bf(Wm[i]);
}

// h (f32 [N][128]) -> packed bf16 pairs (uint [N][64])
__global__ void convh_kernel(const float* __restrict__ h, unsigned* __restrict__ h_bf) {
  int i = blockIdx.x * blockDim.x + threadIdx.x;
  if (i < N_NODES * D / 4) {
    float4 f = ((const float4*)h)[i];
    unsigned lo = ((unsigned)f2bf(f.y) << 16) | f2bf(f.x);
    unsigned hi = ((unsigned)f2bf(f.w) << 16) | f2bf(f.z);
    ((uint2*)h_bf)[i] = make_uint2(lo, hi);
  }
}

// ---------------- aggregate: mean of h[src]*w by dst, then tanh ----------------
// One 64-lane wave per node; lane owns channels {2*lane, 2*lane+1} packed in a uint.
__global__ __launch_bounds__(256) void aggregate_bf_kernel(const unsigned* __restrict__ h_bf,
                                                           const int* __restrict__ csr_src,
                                                           const float* __restrict__ csr_w,
                                                           const int* __restrict__ row_start,
                                                           float* __restrict__ hact) {
  int node = blockIdx.x * 4 + (threadIdx.x >> 6);
  int lane = threadIdx.x & 63;
  if (node >= N_NODES) return;
  int beg = row_start[node], end = row_start[node + 1];
  float a0 = 0.f, a1 = 0.f;
  int e = beg;
  for (; e + 4 <= end; e += 4) {
    int   s0 = csr_src[e],   s1 = csr_src[e+1], s2 = csr_src[e+2], s3 = csr_src[e+3];
    float w0 = csr_w[e],     w1 = csr_w[e+1],   w2 = csr_w[e+2],   w3 = csr_w[e+3];
    unsigned v0 = h_bf[s0 * 64 + lane];
    unsigned v1 = h_bf[s1 * 64 + lane];
    unsigned v2 = h_bf[s2 * 64 + lane];
    unsigned v3 = h_bf[s3 * 64 + lane];
    a0 = fmaf(__uint_as_float(v0 << 16), w0, a0);
    a1 = fmaf(__uint_as_float(v0 & 0xFFFF0000u), w0, a1);
    a0 = fmaf(__uint_as_float(v1 << 16), w1, a0);
    a1 = fmaf(__uint_as_float(v1 & 0xFFFF0000u), w1, a1);
    a0 = fmaf(__uint_as_float(v2 << 16), w2, a0);
    a1 = fmaf(__uint_as_float(v2 & 0xFFFF0000u), w2, a1);
    a0 = fmaf(__uint_as_float(v3 << 16), w3, a0);
    a1 = fmaf(__uint_as_float(v3 & 0xFFFF0000u), w3, a1);
  }
  for (; e < end; ++e) {
    float we = csr_w[e];
    unsigned v = h_bf[csr_src[e] * 64 + lane];
    a0 = fmaf(__uint_as_float(v << 16), we, a0);
    a1 = fmaf(__uint_as_float(v & 0xFFFF0000u), we, a1);
  }
  int deg = end - beg;
  float inv = (deg > 0) ? 1.f / (float)deg : 0.f;
  float2 r;
  r.x = tanhf(a0 * inv);
  r.y = tanhf(a1 * inv);
  ((float2*)hact)[node * 64 + lane] = r;
}

// ---------------- out = tanh-act @ W^T + b via MFMA bf16, in place on d_out ----
__global__ __launch_bounds__(256) void gemm_kernel(const float* __restrict__ hact,
                                                   const unsigned short* __restrict__ W_bf,
                                                   const float* __restrict__ bias,
                                                   float* __restrict__ out) {
  int lane = threadIdx.x & 63;
  int wid  = threadIdx.x >> 6;
  int n_base = blockIdx.x * 64 + wid * 16;
  int m  = lane & 15;   // A row / D col index
  int kg = lane >> 4;   // k-group (8 elems each)
  int n = n_base + m;
  int n_c = (n < N_NODES) ? n : (N_NODES - 1);

  bf16x8 afrag[4];
  const float* arow = hact + (size_t)n_c * D;
#pragma unroll
  for (int kc = 0; kc < 4; ++kc) {
    int k0 = kc * 32 + kg * 8;
    float4 lo = *(const float4*)(arow + k0);
    float4 hi = *(const float4*)(arow + k0 + 4);
    bf16x8 a;
    a[0] = (short)f2bf(lo.x); a[1] = (short)f2bf(lo.y);
    a[2] = (short)f2bf(lo.z); a[3] = (short)f2bf(lo.w);
    a[4] = (short)f2bf(hi.x); a[5] = (short)f2bf(hi.y);
    a[6] = (short)f2bf(hi.z); a[7] = (short)f2bf(hi.w);
    afrag[kc] = a;
  }

#pragma unroll
  for (int jt = 0; jt < 8; ++jt) {
    int j = jt * 16 + m;
    const unsigned short* wrow = W_bf + j * D;
    f32x4 acc = {0.f, 0.f, 0.f, 0.f};
#pragma unroll
    for (int kc = 0; kc < 4; ++kc) {
      bf16x8 b = *(const bf16x8*)(wrow + kc * 32 + kg * 8);
      acc = __builtin_amdgcn_mfma_f32_16x16x32_bf16(afrag[kc], b, acc, 0, 0, 0);
    }
    float bj = bias[j];
#pragma unroll
    for (int r = 0; r < 4; ++r) {
      int nn = n_base + kg * 4 + r;  // C/D: col=lane&15, row=(lane>>4)*4+reg
      if (nn < N_NODES) out[(size_t)nn * D + j] = acc[r] + bj;
    }
  }
}

extern "C" void kernel_launch(void* const* d_in, const int* in_sizes, int n_in,
                              void* d_out, int out_size, void* d_ws, size_t ws_size,
                              hipStream_t stream) {
  const float* h    = (const float*)d_in[0];
  const float* w    = (const float*)d_in[1];
  const int*   src  = (const int*)d_in[2];
  const int*   dst  = (const int*)d_in[3];
  const float* Wm   = (const float*)d_in[4];
  const float* bias = (const float*)d_in[5];
  float* out = (float*)d_out;

  // ws layout (16B-aligned), N_PAD = 50176:
  //   count:     [0,        200704)   (padded, int)
  //   row_start: [200704,   401408)   (padded, int; row_start[N] valid)
  //   cursor:    [401408,   602112)   (padded, int)
  //   blocksum:  [602112,   602368)
  //   blockoff:  [602368,   602624)
  //   csr_src:   [602624,   3802624)
  //   csr_w:     [3802624,  7002624)
  //   W_bf:      [7002624,  7035392)
  //   h_bf:      [7035392,  19835392)
  char* ws = (char*)d_ws;
  int*            count     = (int*)(ws);
  int*            row_start = (int*)(ws + 200704);
  int*            cursor    = (int*)(ws + 401408);
  int*            blocksum  = (int*)(ws + 602112);
  int*            blockoff  = (int*)(ws + 602368);
  int*            csr_src   = (int*)(ws + 602624);
  float*          csr_w     = (float*)(ws + 3802624);
  unsigned short* W_bf      = (unsigned short*)(ws + 7002624);
  unsigned*       h_bf      = (unsigned*)(ws + 7035392);

  hipMemsetAsync(count, 0, N_PAD * sizeof(int), stream);
  convw_kernel<<<(D * D + 255) / 256, 256, 0, stream>>>(Wm, W_bf);
  convh_kernel<<<(N_NODES * D / 4 + 255) / 256, 256, 0, stream>>>(h, h_bf);
  hist_kernel<<<(N_EDGES + 255) / 256, 256, 0, stream>>>(dst, count);
  scan_part1<<<SCAN_BLOCKS, 256, 0, stream>>>((const int4*)count, blocksum);
  scan_part2<<<1, 64, 0, stream>>>(blocksum, blockoff);
  scan_part3<<<SCAN_BLOCKS, 256, 0, stream>>>((const int4*)count, blockoff,
                                              (int4*)row_start, (int4*)cursor);
  scatter_kernel<<<(N_EDGES + 255) / 256, 256, 0, stream>>>(src, dst, w, cursor, csr_src, csr_w);
  aggregate_bf_kernel<<<(N_NODES + 3) / 4, 256, 0, stream>>>(h_bf, csr_src, csr_w, row_start, out);
  gemm_kernel<<<(N_NODES + 63) / 64, 256, 0, stream>>>(out, W_bf, bias, out);
}

// Round 4
// 168.276 us; speedup vs baseline: 1.7757x; 1.0678x over previous
//
#include <hip/hip_runtime.h>
#include <hip/hip_bf16.h>

#define N_NODES 50000
#define N_EDGES 800000
#define D 128
#define SCAN_BLOCKS 49   // 49 * 1024 = 50176 >= N_NODES (padded)
#define N_PAD 50176

typedef __attribute__((ext_vector_type(8))) short bf16x8;
typedef __attribute__((ext_vector_type(4))) float f32x4;

__device__ inline unsigned short f2bf(float f) {
  unsigned u = __float_as_uint(f);
  unsigned r = (u + 0x7FFFu + ((u >> 16) & 1u)) >> 16;
  return (unsigned short)r;
}

// ---------------- prep: h f32 -> packed bf16 table, + dst histogram ----------------
// grid covers N*D/4 = 1.6M float4 conversions; first 800k threads also do hist.
__global__ __launch_bounds__(256) void prep_kernel(const float* __restrict__ h,
                                                   unsigned* __restrict__ h_bf,
                                                   const int* __restrict__ dst,
                                                   int* __restrict__ count) {
  int i = blockIdx.x * blockDim.x + threadIdx.x;
  if (i < N_NODES * D / 4) {
    float4 f = ((const float4*)h)[i];
    unsigned lo = ((unsigned)f2bf(f.y) << 16) | f2bf(f.x);
    unsigned hi = ((unsigned)f2bf(f.w) << 16) | f2bf(f.z);
    ((uint2*)h_bf)[i] = make_uint2(lo, hi);
  }
  if (i < N_EDGES) atomicAdd(&count[dst[i]], 1);
}

// ---------------- scan (3 dispatches) ----------------

__global__ __launch_bounds__(256) void scan_part1(const int4* __restrict__ count4,
                                                  int* __restrict__ blocksum) {
  __shared__ int wsum[4];
  int b = blockIdx.x, t = threadIdx.x;
  int lane = t & 63, wid = t >> 6;
  int4 v = count4[b * 256 + t];
  int s = v.x + v.y + v.z + v.w;
#pragma unroll
  for (int off = 32; off >= 1; off >>= 1) s += __shfl_xor(s, off, 64);
  if (lane == 0) wsum[wid] = s;
  __syncthreads();
  if (t == 0) blocksum[b] = wsum[0] + wsum[1] + wsum[2] + wsum[3];
}

// wave 0: scan 49 block sums; all 1024 threads: convert W to bf16.
__global__ __launch_bounds__(1024) void scan2_convw(const int* __restrict__ blocksum,
                                                    int* __restrict__ blockoff,
                                                    const float4* __restrict__ Wm4,
                                                    ushort4* __restrict__ W4) {
  int t = threadIdx.x;
  if (t < 64) {
    int v = (t < SCAN_BLOCKS) ? blocksum[t] : 0;
    int incl = v;
#pragma unroll
    for (int off = 1; off < 64; off <<= 1) {
      int y = __shfl_up(incl, off, 64);
      if (t >= off) incl += y;
    }
    if (t < SCAN_BLOCKS) blockoff[t] = incl - v;
  }
#pragma unroll
  for (int i = t; i < D * D / 4; i += 1024) {
    float4 f = Wm4[i];
    ushort4 o;
    o.x = f2bf(f.x); o.y = f2bf(f.y); o.z = f2bf(f.z); o.w = f2bf(f.w);
    W4[i] = o;
  }
}

__global__ __launch_bounds__(256) void scan_part3(const int4* __restrict__ count4,
                                                  const int* __restrict__ blockoff,
                                                  int4* __restrict__ row4,
                                                  int4* __restrict__ cur4) {
  __shared__ int wsum[4];
  int b = blockIdx.x, t = threadIdx.x;
  int lane = t & 63, wid = t >> 6;
  int4 v = count4[b * 256 + t];
  int s = v.x + v.y + v.z + v.w;
  int incl = s;
#pragma unroll
  for (int off = 1; off < 64; off <<= 1) {
    int y = __shfl_up(incl, off, 64);
    if (lane >= off) incl += y;
  }
  if (lane == 63) wsum[wid] = incl;
  __syncthreads();
  int woff = 0;
#pragma unroll
  for (int i = 0; i < 4; ++i) woff += (i < wid) ? wsum[i] : 0;
  int excl = incl - s + woff + blockoff[b];
  int4 p;
  p.x = excl;
  p.y = p.x + v.x;
  p.z = p.y + v.y;
  p.w = p.z + v.z;
  row4[b * 256 + t] = p;
  cur4[b * 256 + t] = p;
}

// ---------------- scatter: ONE packed 4B word per edge ----------------
// entry = (src << 16) | round(w * 65535); w in [0,1) -> err <= 7.6e-6.
__global__ void scatter_kernel(const int* __restrict__ src, const int* __restrict__ dst,
                               const float* __restrict__ w, int* __restrict__ cursor,
                               unsigned* __restrict__ csr_ew) {
  int e = blockIdx.x * blockDim.x + threadIdx.x;
  if (e < N_EDGES) {
    int pos = atomicAdd(&cursor[dst[e]], 1);
    unsigned q = (unsigned)__float2uint_rn(w[e] * 65535.f);
    csr_ew[pos] = ((unsigned)src[e] << 16) | q;
  }
}

// ---------------- aggregate: mean of h[src]*w by dst, then tanh ----------------
// One 64-lane wave per node; lane owns channels {2*lane, 2*lane+1} packed in a uint.
__global__ __launch_bounds__(256) void aggregate_kernel(const unsigned* __restrict__ h_bf,
                                                        const unsigned* __restrict__ csr_ew,
                                                        const int* __restrict__ row_start,
                                                        float* __restrict__ hact) {
  int node = blockIdx.x * 4 + (threadIdx.x >> 6);
  int lane = threadIdx.x & 63;
  if (node >= N_NODES) return;
  int beg = row_start[node], end = row_start[node + 1];
  const float WS = 1.0f / 65535.0f;
  float a0 = 0.f, a1 = 0.f;
  int e = beg;
  for (; e + 4 <= end; e += 4) {
    unsigned p0 = csr_ew[e],   p1 = csr_ew[e+1], p2 = csr_ew[e+2], p3 = csr_ew[e+3];
    unsigned v0 = h_bf[(p0 >> 16) * 64 + lane];
    unsigned v1 = h_bf[(p1 >> 16) * 64 + lane];
    unsigned v2 = h_bf[(p2 >> 16) * 64 + lane];
    unsigned v3 = h_bf[(p3 >> 16) * 64 + lane];
    float w0 = (float)(p0 & 0xFFFFu) * WS;
    float w1 = (float)(p1 & 0xFFFFu) * WS;
    float w2 = (float)(p2 & 0xFFFFu) * WS;
    float w3 = (float)(p3 & 0xFFFFu) * WS;
    a0 = fmaf(__uint_as_float(v0 << 16), w0, a0);
    a1 = fmaf(__uint_as_float(v0 & 0xFFFF0000u), w0, a1);
    a0 = fmaf(__uint_as_float(v1 << 16), w1, a0);
    a1 = fmaf(__uint_as_float(v1 & 0xFFFF0000u), w1, a1);
    a0 = fmaf(__uint_as_float(v2 << 16), w2, a0);
    a1 = fmaf(__uint_as_float(v2 & 0xFFFF0000u), w2, a1);
    a0 = fmaf(__uint_as_float(v3 << 16), w3, a0);
    a1 = fmaf(__uint_as_float(v3 & 0xFFFF0000u), w3, a1);
  }
  for (; e < end; ++e) {
    unsigned p = csr_ew[e];
    unsigned v = h_bf[(p >> 16) * 64 + lane];
    float we = (float)(p & 0xFFFFu) * WS;
    a0 = fmaf(__uint_as_float(v << 16), we, a0);
    a1 = fmaf(__uint_as_float(v & 0xFFFF0000u), we, a1);
  }
  int deg = end - beg;
  float inv = (deg > 0) ? 1.f / (float)deg : 0.f;
  float2 r;
  r.x = tanhf(a0 * inv);
  r.y = tanhf(a1 * inv);
  ((float2*)hact)[node * 64 + lane] = r;
}

// ---------------- out = tanh-act @ W^T + b via MFMA bf16, in place on d_out ----
__global__ __launch_bounds__(256) void gemm_kernel(const float* __restrict__ hact,
                                                   const unsigned short* __restrict__ W_bf,
                                                   const float* __restrict__ bias,
                                                   float* __restrict__ out) {
  int lane = threadIdx.x & 63;
  int wid  = threadIdx.x >> 6;
  int n_base = blockIdx.x * 64 + wid * 16;
  int m  = lane & 15;   // A row / D col index
  int kg = lane >> 4;   // k-group (8 elems each)
  int n = n_base + m;
  int n_c = (n < N_NODES) ? n : (N_NODES - 1);

  bf16x8 afrag[4];
  const float* arow = hact + (size_t)n_c * D;
#pragma unroll
  for (int kc = 0; kc < 4; ++kc) {
    int k0 = kc * 32 + kg * 8;
    float4 lo = *(const float4*)(arow + k0);
    float4 hi = *(const float4*)(arow + k0 + 4);
    bf16x8 a;
    a[0] = (short)f2bf(lo.x); a[1] = (short)f2bf(lo.y);
    a[2] = (short)f2bf(lo.z); a[3] = (short)f2bf(lo.w);
    a[4] = (short)f2bf(hi.x); a[5] = (short)f2bf(hi.y);
    a[6] = (short)f2bf(hi.z); a[7] = (short)f2bf(hi.w);
    afrag[kc] = a;
  }

#pragma unroll
  for (int jt = 0; jt < 8; ++jt) {
    int j = jt * 16 + m;
    const unsigned short* wrow = W_bf + j * D;
    f32x4 acc = {0.f, 0.f, 0.f, 0.f};
#pragma unroll
    for (int kc = 0; kc < 4; ++kc) {
      bf16x8 b = *(const bf16x8*)(wrow + kc * 32 + kg * 8);
      acc = __builtin_amdgcn_mfma_f32_16x16x32_bf16(afrag[kc], b, acc, 0, 0, 0);
    }
    float bj = bias[j];
#pragma unroll
    for (int r = 0; r < 4; ++r) {
      int nn = n_base + kg * 4 + r;  // C/D: col=lane&15, row=(lane>>4)*4+reg
      if (nn < N_NODES) out[(size_t)nn * D + j] = acc[r] + bj;
    }
  }
}

extern "C" void kernel_launch(void* const* d_in, const int* in_sizes, int n_in,
                              void* d_out, int out_size, void* d_ws, size_t ws_size,
                              hipStream_t stream) {
  const float* h    = (const float*)d_in[0];
  const float* w    = (const float*)d_in[1];
  const int*   src  = (const int*)d_in[2];
  const int*   dst  = (const int*)d_in[3];
  const float* Wm   = (const float*)d_in[4];
  const float* bias = (const float*)d_in[5];
  float* out = (float*)d_out;

  // ws layout (16B-aligned), N_PAD = 50176:
  //   count:     [0,        200704)   (padded int)
  //   row_start: [200704,   401408)   (padded int; row_start[N] valid)
  //   cursor:    [401408,   602112)   (padded int)
  //   blocksum:  [602112,   602368)
  //   blockoff:  [602368,   602624)
  //   csr_ew:    [602624,   3802624)  (packed src<<16 | w_q16)
  //   W_bf:      [3802624,  3835392)
  //   h_bf:      [3835392,  16635392)
  char* ws = (char*)d_ws;
  int*            count     = (int*)(ws);
  int*            row_start = (int*)(ws + 200704);
  int*            cursor    = (int*)(ws + 401408);
  int*            blocksum  = (int*)(ws + 602112);
  int*            blockoff  = (int*)(ws + 602368);
  unsigned*       csr_ew    = (unsigned*)(ws + 602624);
  unsigned short* W_bf      = (unsigned short*)(ws + 3802624);
  unsigned*       h_bf      = (unsigned*)(ws + 3835392);

  hipMemsetAsync(count, 0, N_PAD * sizeof(int), stream);
  prep_kernel<<<(N_NODES * D / 4 + 255) / 256, 256, 0, stream>>>(h, h_bf, dst, count);
  scan_part1<<<SCAN_BLOCKS, 256, 0, stream>>>((const int4*)count, blocksum);
  scan2_convw<<<1, 1024, 0, stream>>>(blocksum, blockoff, (const float4*)Wm, (ushort4*)W_bf);
  scan_part3<<<SCAN_BLOCKS, 256, 0, stream>>>((const int4*)count, blockoff,
                                              (int4*)row_start, (int4*)cursor);
  scatter_kernel<<<(N_EDGES + 255) / 256, 256, 0, stream>>>(src, dst, w, cursor, csr_ew);
  aggregate_kernel<<<(N_NODES + 3) / 4, 256, 0, stream>>>(h_bf, csr_ew, row_start, out);
  gemm_kernel<<<(N_NODES + 63) / 64, 256, 0, stream>>>(out, W_bf, bias, out);
}